// Round 1
// baseline (1021.454 us; speedup 1.0000x reference)
//
#include <hip/hip_runtime.h>
#include <hip/hip_bf16.h>

#define NODES_F 64   // feature dim (both layers)
#define NGRAPH  64
#define TOPO_D  16
#define NCLS    4

// ---------------- degree ----------------
__global__ void deg_kernel(const int* __restrict__ dst, int* __restrict__ degi, int E) {
    int e = blockIdx.x * blockDim.x + threadIdx.x;
    if (e < E) atomicAdd(&degi[dst[e]], 1);
}

__global__ void dis_kernel(const int* __restrict__ degi, float* __restrict__ dis, int N) {
    int i = blockIdx.x * blockDim.x + threadIdx.x;
    if (i < N) dis[i] = rsqrtf((float)degi[i] + 1.0f);
}

// ---------------- GEMM: Y[i][f] = (sum_k X[i][k] * W[k][f]) * dis[i] ----------------
// block = 256 threads = 4 rows x 64 feats; each block does 16 rows (4 iters).
__global__ __launch_bounds__(256) void gemm_scale_kernel(
        const float* __restrict__ X, const float* __restrict__ W,
        const float* __restrict__ dis, float* __restrict__ Y, int N) {
    __shared__ float Ws[64 * 64];
    __shared__ float Xs[4][64];
    int tid = threadIdx.x;
    for (int i = tid; i < 64 * 64; i += 256) Ws[i] = W[i];
    int r = tid >> 6;       // 0..3 (one wave per row)
    int f = tid & 63;
    int rowBase = blockIdx.x * 16;
    for (int it = 0; it < 4; ++it) {
        int row = rowBase + it * 4 + r;
        __syncthreads();                         // Ws ready / prev Xs reads done
        if (row < N) Xs[r][f] = X[(long long)row * 64 + f];
        __syncthreads();
        if (row < N) {
            float acc = 0.0f;
            #pragma unroll
            for (int k = 0; k < 64; ++k) acc += Xs[r][k] * Ws[k * 64 + f];
            Y[(long long)row * 64 + f] = acc * dis[row];
        }
    }
}

// ---------------- scatter: B[dst[e]][f] += A[src[e]][f] ----------------
__global__ __launch_bounds__(256) void scatter_kernel(
        const float* __restrict__ A, float* __restrict__ B,
        const int* __restrict__ src, const int* __restrict__ dst, int total) {
    int idx = blockIdx.x * blockDim.x + threadIdx.x;
    if (idx >= total) return;
    int e = idx >> 6;
    int f = idx & 63;
    int s = src[e];
    int d = dst[e];
    unsafeAtomicAdd(&B[(long long)d * 64 + f], A[(long long)s * 64 + f]);
}

// ---------------- finalize: B = relu(dis*(B + A) + bias) ----------------
__global__ __launch_bounds__(256) void finalize_kernel(
        float* __restrict__ B, const float* __restrict__ A,
        const float* __restrict__ dis, const float* __restrict__ bias, int N) {
    int idx = blockIdx.x * blockDim.x + threadIdx.x;
    if (idx >= N * 64) return;
    int row = idx >> 6;
    int f = idx & 63;
    float v = dis[row] * (B[idx] + A[idx]) + bias[f];
    B[idx] = v > 0.0f ? v : 0.0f;
}

// ---------------- pool: run-length accumulate over sorted batch ----------------
// one wave handles 128 contiguous nodes; lane = feature.
__global__ __launch_bounds__(256) void pool_kernel(
        const float* __restrict__ H, const int* __restrict__ batch,
        float* __restrict__ gsum, float* __restrict__ gcnt, int N) {
    int wave = (blockIdx.x * blockDim.x + threadIdx.x) >> 6;
    int lane = threadIdx.x & 63;
    int n0 = wave * 128;
    if (n0 >= N) return;
    int n1 = min(n0 + 128, N);
    int cur = batch[n0];
    float acc = 0.0f, cnt = 0.0f;
    for (int n = n0; n < n1; ++n) {
        int g = batch[n];
        if (g != cur) {
            unsafeAtomicAdd(&gsum[cur * 64 + lane], acc);
            if (lane == 0) unsafeAtomicAdd(&gcnt[cur], cnt);
            acc = 0.0f; cnt = 0.0f; cur = g;
        }
        acc += H[(long long)n * 64 + lane];
        cnt += 1.0f;
    }
    unsafeAtomicAdd(&gsum[cur * 64 + lane], acc);
    if (lane == 0) unsafeAtomicAdd(&gcnt[cur], cnt);
}

// ---------------- head: out[g][c] = mean-pool concat topo @ Wlin + blin ----------------
__global__ __launch_bounds__(256) void head_kernel(
        const float* __restrict__ gsum, const float* __restrict__ gcnt,
        const float* __restrict__ topo, const float* __restrict__ Wlin,
        const float* __restrict__ blin, float* __restrict__ out) {
    int t = threadIdx.x;              // 256 = 64 graphs x 4 classes
    int g = t >> 2;
    int c = t & 3;
    float inv = 1.0f / fmaxf(gcnt[g], 1.0f);
    float v = blin[c];
    #pragma unroll
    for (int f = 0; f < 64; ++f) v += gsum[g * 64 + f] * inv * Wlin[f * 4 + c];
    #pragma unroll
    for (int t2 = 0; t2 < TOPO_D; ++t2) v += topo[g * TOPO_D + t2] * Wlin[(64 + t2) * 4 + c];
    out[g * 4 + c] = v;
}

extern "C" void kernel_launch(void* const* d_in, const int* in_sizes, int n_in,
                              void* d_out, int out_size, void* d_ws, size_t ws_size,
                              hipStream_t stream) {
    const float* x     = (const float*)d_in[0];
    const int*   ei    = (const int*)d_in[1];
    const int*   batch = (const int*)d_in[2];
    const float* topo  = (const float*)d_in[3];
    const float* W1    = (const float*)d_in[4];
    const float* b1    = (const float*)d_in[5];
    const float* W2    = (const float*)d_in[6];
    const float* b2    = (const float*)d_in[7];
    const float* Wlin  = (const float*)d_in[8];
    const float* blin  = (const float*)d_in[9];
    float* out = (float*)d_out;

    const int N = in_sizes[0] / 64;      // 100000
    const int E = in_sizes[1] / 2;       // 1600000
    const int* src = ei;
    const int* dst = ei + E;

    // workspace layout (bytes), 256-aligned
    char* ws = (char*)d_ws;
    size_t offA    = 0;                          // A: N*64 f32 (scaled XW)
    size_t offB    = offA + (size_t)N * 64 * 4;  // B: N*64 f32 (scatter acc / h)
    size_t offDis  = offB + (size_t)N * 64 * 4;  // dis: N f32
    size_t offDeg  = offDis + (size_t)N * 4;     // degi: N i32
    size_t offGsum = offDeg + (size_t)N * 4;     // gsum: 64*64 f32
    size_t offGcnt = offGsum + (size_t)NGRAPH * 64 * 4; // gcnt: 64 f32
    float* A    = (float*)(ws + offA);
    float* B    = (float*)(ws + offB);
    float* dis  = (float*)(ws + offDis);
    int*   degi = (int*)(ws + offDeg);
    float* gsum = (float*)(ws + offGsum);
    float* gcnt = (float*)(ws + offGcnt);

    const int NF = N * 64;               // 6.4M
    const int EF = E * 64;               // 102.4M

    // zero accumulators (ws is poisoned with 0xAA every call)
    hipMemsetAsync(degi, 0, (size_t)N * 4, stream);
    hipMemsetAsync(gsum, 0, (size_t)(NGRAPH * 64 + NGRAPH) * 4, stream);  // gsum+gcnt contiguous

    // degree + normalization
    deg_kernel<<<(E + 255) / 256, 256, 0, stream>>>(dst, degi, E);
    dis_kernel<<<(N + 255) / 256, 256, 0, stream>>>(degi, dis, N);

    // ---- layer 1 ----
    hipMemsetAsync(B, 0, (size_t)NF * 4, stream);
    gemm_scale_kernel<<<(N + 15) / 16, 256, 0, stream>>>(x, W1, dis, A, N);
    scatter_kernel<<<(EF + 255) / 256, 256, 0, stream>>>(A, B, src, dst, EF);
    finalize_kernel<<<(NF + 255) / 256, 256, 0, stream>>>(B, A, dis, b1, N);

    // ---- layer 2 ---- (reads B=h1, writes A; then B becomes acc2)
    gemm_scale_kernel<<<(N + 15) / 16, 256, 0, stream>>>(B, W2, dis, A, N);
    hipMemsetAsync(B, 0, (size_t)NF * 4, stream);
    scatter_kernel<<<(EF + 255) / 256, 256, 0, stream>>>(A, B, src, dst, EF);
    finalize_kernel<<<(NF + 255) / 256, 256, 0, stream>>>(B, A, dis, b2, N);

    // ---- pool + head ----
    int waves = (N + 127) / 128;
    pool_kernel<<<(waves + 3) / 4, 256, 0, stream>>>(B, batch, gsum, gcnt, N);
    head_kernel<<<1, 256, 0, stream>>>(gsum, gcnt, topo, Wlin, blin, out);
}

// Round 2
// 618.110 us; speedup vs baseline: 1.6525x; 1.6525x over previous
//
#include <hip/hip_runtime.h>
#include <hip/hip_bf16.h>

#define NGRAPH  64
#define TOPO_D  16

// ---------------- degree histogram (in-degree, no self-loop) ----------------
__global__ void deg_kernel(const int* __restrict__ dst, int* __restrict__ degi, int E) {
    int e = blockIdx.x * blockDim.x + threadIdx.x;
    if (e < E) atomicAdd(&degi[dst[e]], 1);
}

__global__ void dis_kernel(const int* __restrict__ degi, float* __restrict__ dis, int N) {
    int i = blockIdx.x * blockDim.x + threadIdx.x;
    if (i < N) dis[i] = rsqrtf((float)degi[i] + 1.0f);
}

// ---------------- exclusive scan of degi -> rowptr (3-phase) ----------------
// Phase A: per-block (1024 elems) exclusive scan, block totals to bsum.
__global__ __launch_bounds__(256) void scanA_kernel(
        const int* __restrict__ degi, int* __restrict__ rowptr,
        int* __restrict__ bsum, int N) {
    __shared__ int sdata[256];
    int tid = threadIdx.x;
    int base = blockIdx.x * 1024 + tid * 4;
    int d0 = (base + 0 < N) ? degi[base + 0] : 0;
    int d1 = (base + 1 < N) ? degi[base + 1] : 0;
    int d2 = (base + 2 < N) ? degi[base + 2] : 0;
    int d3 = (base + 3 < N) ? degi[base + 3] : 0;
    int tsum = d0 + d1 + d2 + d3;
    sdata[tid] = tsum;
    __syncthreads();
    for (int off = 1; off < 256; off <<= 1) {
        int v = (tid >= off) ? sdata[tid - off] : 0;
        __syncthreads();
        sdata[tid] += v;
        __syncthreads();
    }
    int run = sdata[tid] - tsum;   // exclusive prefix of thread sums
    if (tid == 255) bsum[blockIdx.x] = sdata[255];
    if (base + 0 < N) rowptr[base + 0] = run; run += d0;
    if (base + 1 < N) rowptr[base + 1] = run; run += d1;
    if (base + 2 < N) rowptr[base + 2] = run; run += d2;
    if (base + 3 < N) rowptr[base + 3] = run;
}

// Phase B: serial exclusive scan of block sums (nb ~ 98, trivial).
__global__ void scanB_kernel(int* __restrict__ bsum, int nb) {
    if (threadIdx.x == 0 && blockIdx.x == 0) {
        int run = 0;
        for (int i = 0; i < nb; ++i) { int v = bsum[i]; bsum[i] = run; run += v; }
    }
}

// Phase C: add block offsets; init write cursors; set rowptr[N] = E.
__global__ void scanC_kernel(int* __restrict__ rowptr, const int* __restrict__ bsum,
                             int* __restrict__ wpos, int N, int E) {
    int i = blockIdx.x * blockDim.x + threadIdx.x;
    if (i < N) {
        int v = rowptr[i] + bsum[i >> 10];
        rowptr[i] = v;
        wpos[i] = v;
    }
    if (i == 0) rowptr[N] = E;
}

// ---------------- CSR fill: col[pos] = src, grouped by dst ----------------
__global__ void fill_kernel(const int* __restrict__ src, const int* __restrict__ dst,
                            int* __restrict__ wpos, int* __restrict__ col, int E) {
    int e = blockIdx.x * blockDim.x + threadIdx.x;
    if (e < E) {
        int pos = atomicAdd(&wpos[dst[e]], 1);
        col[pos] = src[e];
    }
}

// ---------------- GEMM: Y[i][f] = (sum_k X[i][k] * W[k][f]) * dis[i] ----------------
__global__ __launch_bounds__(256) void gemm_scale_kernel(
        const float* __restrict__ X, const float* __restrict__ W,
        const float* __restrict__ dis, float* __restrict__ Y, int N) {
    __shared__ float Ws[64 * 64];
    __shared__ float Xs[4][64];
    int tid = threadIdx.x;
    for (int i = tid; i < 64 * 64; i += 256) Ws[i] = W[i];
    int r = tid >> 6;
    int f = tid & 63;
    int rowBase = blockIdx.x * 16;
    for (int it = 0; it < 4; ++it) {
        int row = rowBase + it * 4 + r;
        __syncthreads();
        if (row < N) Xs[r][f] = X[(long long)row * 64 + f];
        __syncthreads();
        if (row < N) {
            float acc = 0.0f;
            #pragma unroll
            for (int k = 0; k < 64; ++k) acc += Xs[r][k] * Ws[k * 64 + f];
            Y[(long long)row * 64 + f] = acc * dis[row];
        }
    }
}

// ---------------- pull: B[i] = relu(dis[i]*(A[i] + sum_{e in CSR[i]} A[col[e]]) + bias)
// one wave per node; lane = feature. A rows are 256B, coalesced; no atomics.
__global__ __launch_bounds__(256) void pull_kernel(
        const float* __restrict__ A, float* __restrict__ B,
        const int* __restrict__ rowptr, const int* __restrict__ col,
        const float* __restrict__ dis, const float* __restrict__ bias, int N) {
    int wave = (blockIdx.x * blockDim.x + threadIdx.x) >> 6;
    int lane = threadIdx.x & 63;
    if (wave >= N) return;
    int node = wave;
    int beg = rowptr[node];
    int end = rowptr[node + 1];
    float acc0 = A[(long long)node * 64 + lane];   // self-loop (A pre-scaled by dis)
    float acc1 = 0.0f;
    int e = beg;
    for (; e + 1 < end; e += 2) {
        int s0 = col[e];
        int s1 = col[e + 1];
        float v0 = A[(long long)s0 * 64 + lane];
        float v1 = A[(long long)s1 * 64 + lane];
        acc0 += v0;
        acc1 += v1;
    }
    if (e < end) acc0 += A[(long long)col[e] * 64 + lane];
    float v = dis[node] * (acc0 + acc1) + bias[lane];
    B[(long long)node * 64 + lane] = v > 0.0f ? v : 0.0f;
}

// ---------------- pool: run-length accumulate over sorted batch ----------------
__global__ __launch_bounds__(256) void pool_kernel(
        const float* __restrict__ H, const int* __restrict__ batch,
        float* __restrict__ gsum, float* __restrict__ gcnt, int N) {
    int wave = (blockIdx.x * blockDim.x + threadIdx.x) >> 6;
    int lane = threadIdx.x & 63;
    int n0 = wave * 128;
    if (n0 >= N) return;
    int n1 = min(n0 + 128, N);
    int cur = batch[n0];
    float acc = 0.0f, cnt = 0.0f;
    for (int n = n0; n < n1; ++n) {
        int g = batch[n];
        if (g != cur) {
            unsafeAtomicAdd(&gsum[cur * 64 + lane], acc);
            if (lane == 0) unsafeAtomicAdd(&gcnt[cur], cnt);
            acc = 0.0f; cnt = 0.0f; cur = g;
        }
        acc += H[(long long)n * 64 + lane];
        cnt += 1.0f;
    }
    unsafeAtomicAdd(&gsum[cur * 64 + lane], acc);
    if (lane == 0) unsafeAtomicAdd(&gcnt[cur], cnt);
}

// ---------------- head ----------------
__global__ __launch_bounds__(256) void head_kernel(
        const float* __restrict__ gsum, const float* __restrict__ gcnt,
        const float* __restrict__ topo, const float* __restrict__ Wlin,
        const float* __restrict__ blin, float* __restrict__ out) {
    int t = threadIdx.x;              // 256 = 64 graphs x 4 classes
    int g = t >> 2;
    int c = t & 3;
    float inv = 1.0f / fmaxf(gcnt[g], 1.0f);
    float v = blin[c];
    #pragma unroll
    for (int f = 0; f < 64; ++f) v += gsum[g * 64 + f] * inv * Wlin[f * 4 + c];
    #pragma unroll
    for (int t2 = 0; t2 < TOPO_D; ++t2) v += topo[g * TOPO_D + t2] * Wlin[(64 + t2) * 4 + c];
    out[g * 4 + c] = v;
}

extern "C" void kernel_launch(void* const* d_in, const int* in_sizes, int n_in,
                              void* d_out, int out_size, void* d_ws, size_t ws_size,
                              hipStream_t stream) {
    const float* x     = (const float*)d_in[0];
    const int*   ei    = (const int*)d_in[1];
    const int*   batch = (const int*)d_in[2];
    const float* topo  = (const float*)d_in[3];
    const float* W1    = (const float*)d_in[4];
    const float* b1    = (const float*)d_in[5];
    const float* W2    = (const float*)d_in[6];
    const float* b2    = (const float*)d_in[7];
    const float* Wlin  = (const float*)d_in[8];
    const float* blin  = (const float*)d_in[9];
    float* out = (float*)d_out;

    const int N = in_sizes[0] / 64;      // 100000
    const int E = in_sizes[1] / 2;       // 1600000
    const int* src = ei;
    const int* dst = ei + E;

    // workspace layout (bytes)
    char* ws = (char*)d_ws;
    size_t off = 0;
    float* A      = (float*)(ws + off); off += (size_t)N * 64 * 4;
    float* B      = (float*)(ws + off); off += (size_t)N * 64 * 4;
    float* dis    = (float*)(ws + off); off += (size_t)N * 4;
    int*   degi   = (int*)  (ws + off); off += (size_t)N * 4;
    int*   rowptr = (int*)  (ws + off); off += (size_t)(N + 1) * 4;
    int*   wpos   = (int*)  (ws + off); off += (size_t)N * 4;
    int*   col    = (int*)  (ws + off); off += (size_t)E * 4;
    int*   bsum   = (int*)  (ws + off); off += 1024;
    float* gsum   = (float*)(ws + off); off += (size_t)NGRAPH * 64 * 4;
    float* gcnt   = (float*)(ws + off); off += (size_t)NGRAPH * 4;

    const int nbScan = (N + 1023) / 1024;   // 98

    // zero accumulators (ws is poisoned with 0xAA every call)
    hipMemsetAsync(degi, 0, (size_t)N * 4, stream);
    hipMemsetAsync(gsum, 0, (size_t)(NGRAPH * 64 + NGRAPH) * 4, stream);

    // degree histogram + normalization
    deg_kernel<<<(E + 255) / 256, 256, 0, stream>>>(dst, degi, E);
    dis_kernel<<<(N + 255) / 256, 256, 0, stream>>>(degi, dis, N);

    // CSR build (once; reused by both layers)
    scanA_kernel<<<nbScan, 256, 0, stream>>>(degi, rowptr, bsum, N);
    scanB_kernel<<<1, 64, 0, stream>>>(bsum, nbScan);
    scanC_kernel<<<(N + 255) / 256, 256, 0, stream>>>(rowptr, bsum, wpos, N, E);
    fill_kernel<<<(E + 255) / 256, 256, 0, stream>>>(src, dst, wpos, col, E);

    // ---- layer 1 ----
    gemm_scale_kernel<<<(N + 15) / 16, 256, 0, stream>>>(x, W1, dis, A, N);
    pull_kernel<<<(N + 3) / 4, 256, 0, stream>>>(A, B, rowptr, col, dis, b1, N);

    // ---- layer 2 ----
    gemm_scale_kernel<<<(N + 15) / 16, 256, 0, stream>>>(B, W2, dis, A, N);
    pull_kernel<<<(N + 3) / 4, 256, 0, stream>>>(A, B, rowptr, col, dis, b2, N);

    // ---- pool + head ----
    int waves = (N + 127) / 128;
    pool_kernel<<<(waves + 3) / 4, 256, 0, stream>>>(B, batch, gsum, gcnt, N);
    head_kernel<<<1, 256, 0, stream>>>(gsum, gcnt, topo, Wlin, blin, out);
}